// Round 5
// baseline (22.038 us; speedup 1.0000x reference)
//
#include <hip/hip_runtime.h>

// -------------------------------------------------------------------------
// PhonemeLengthRegulator, single fused homogeneous kernel.
//   per-syllable masked softmax over <=16 phoneme logits, scaled by beat_syb,
//   scattered at exclusive-cumsum(counts) offsets into beat[B, T].
//   Each block (chunk c, batch b):
//    1. computes its base offset = sum(masked counts[0 : c*512)) (coalesced
//       int4 re-read, L2-resident),
//    2. block-scans its 512 counts for local offsets,
//    3. softmax -> LDS stage at packed local offsets,
//    4. writes ONE contiguous span of beat[b,:] out as coalesced float4,
//    5. zeroes its 1/16 slice of the tail [len, T) (disjoint from spans).
//   No workspace, no atomics, no inter-block dependencies.
// -------------------------------------------------------------------------

#define THREADS 512
#define CHUNK   512   // syllables per block (== THREADS, 1 per thread)

__global__ __launch_bounds__(THREADS) void plr_fused(
        const int*   __restrict__ syllable_num,
        const int*   __restrict__ syllable_lengths,
        const float* __restrict__ beat_syb,
        const float* __restrict__ ds_alf,
        const int*   __restrict__ lens,
        float*       __restrict__ beat,
        float*       __restrict__ len_out,
        int S, int T) {
    const int b     = blockIdx.y;
    const int chunk = blockIdx.x;
    const int t     = threadIdx.x;
    const int lane  = t & 63;
    const int wid   = t >> 6;                 // 0..7

    const int slen  = syllable_lengths[b];
    const int len   = lens[b];
    const int* nrow = syllable_num + (size_t)b * S;

    // ---- base offset: sum counts[0 : chunk*CHUNK) masked by slen ----
    int pref = 0;
    {
        const int lim = chunk * CHUNK;        // <= S, multiple of 4
        const int nv4 = lim >> 2;
        const int4* nrow4 = (const int4*)nrow;
        for (int i = t; i < nv4; i += THREADS) {
            int4 v = nrow4[i];
            const int base = i << 2;
            pref += ((base + 0) < slen ? v.x : 0)
                  + ((base + 1) < slen ? v.y : 0)
                  + ((base + 2) < slen ? v.z : 0)
                  + ((base + 3) < slen ? v.w : 0);
        }
        #pragma unroll
        for (int d = 32; d >= 1; d >>= 1) pref += __shfl_xor(pref, d, 64);
    }

    __shared__ int wred[8];
    __shared__ int wsum[8];
    if (lane == 0) wred[wid] = pref;

    // ---- this chunk's counts + block-wide exclusive scan ----
    const int  j    = chunk * CHUNK + t;
    const bool in_s = (j < S);
    const int  n    = in_s ? nrow[j] : 0;                 // 1..16 when valid
    const int  cnt  = (in_s && j < slen) ? n : 0;

    int sc = cnt;                                         // wave inclusive scan
    #pragma unroll
    for (int d = 1; d < 64; d <<= 1) {
        int u = __shfl_up(sc, d, 64);
        if (lane >= d) sc += u;
    }
    if (lane == 63) wsum[wid] = sc;
    __syncthreads();

    int block_base = 0, wbase = 0, span = 0;
    #pragma unroll
    for (int w = 0; w < 8; ++w) {
        block_base += wred[w];
        span       += wsum[w];
        if (w < wid) wbase += wsum[w];
    }
    const int local_off = wbase + sc - cnt;               // exclusive offset

    // ---- masked softmax into LDS stage (packed) ----
    __shared__ float stage[CHUNK * 16];                   // 32 KB
    if (cnt > 0) {
        const size_t sid = (size_t)b * S + j;
        const float4* src = (const float4*)(ds_alf + (sid << 4));
        float4 v0 = src[0], v1 = src[1], v2 = src[2], v3 = src[3];
        float x[16] = { v0.x, v0.y, v0.z, v0.w,
                        v1.x, v1.y, v1.z, v1.w,
                        v2.x, v2.y, v2.z, v2.w,
                        v3.x, v3.y, v3.z, v3.w };
        #pragma unroll
        for (int k = 0; k < 16; ++k)
            if (k >= n) x[k] = -INFINITY;                 // exp -> exactly 0

        float m = x[0];
        #pragma unroll
        for (int k = 1; k < 16; ++k) m = fmaxf(m, x[k]);

        float s = 0.0f;
        #pragma unroll
        for (int k = 0; k < 16; ++k) { x[k] = __expf(x[k] - m); s += x[k]; }

        const float scale = beat_syb[sid] / s;
        #pragma unroll
        for (int k = 0; k < 16; ++k)
            if (k < n) stage[local_off + k] = x[k] * scale;
    }
    __syncthreads();

    // ---- coalesced span write: beat[b, block_base : block_base+span) ----
    float* row = beat + (size_t)b * T;
    if (span > 0) {
        const int gbeg = block_base;
        const int gend = block_base + span;
        const int a0   = (gbeg + 3) & ~3;                 // first aligned f4
        const int a1   = gend & ~3;                       // end of aligned body

        const int hend = (a0 < gend) ? a0 : gend;         // scalar head (<=3)
        if (t < hend - gbeg) row[gbeg + t] = stage[t];

        for (int p = a0 + 4 * t; p + 4 <= gend; p += 4 * THREADS) {
            const int l = p - gbeg;
            *(float4*)(row + p) =
                make_float4(stage[l], stage[l+1], stage[l+2], stage[l+3]);
        }

        const int tb = (a1 > a0) ? a1 : a0;               // scalar tail (<=3)
        if (tb < gend && t < gend - tb)
            row[tb + t] = stage[tb - gbeg + t];
    }

    // ---- zero this block's slice of the tail [len, T) + lengths out ----
    if (chunk == 0 && t == 0) len_out[b] = (float)len;

    const int fq   = len >> 2;                 // first (possibly partial) slot
    const int Qs   = (T >> 2) - fq;            // f4 slots covering the tail
    const int nc   = gridDim.x;
    const int step = (Qs + nc - 1) / nc;
    const int q0   = fq + chunk * step;
    const int q1e  = q0 + step;
    const int q1   = (q1e < (T >> 2)) ? q1e : (T >> 2);
    for (int q = q0 + t; q < q1; q += THREADS) {
        const int pos = q << 2;
        float* p = row + pos;
        if (pos >= len) {
            *(float4*)p = make_float4(0.f, 0.f, 0.f, 0.f);
        } else {                                // only the boundary slot
            #pragma unroll
            for (int k = 0; k < 4; ++k)
                if (pos + k >= len) p[k] = 0.f;
        }
    }
}

extern "C" void kernel_launch(void* const* d_in, const int* in_sizes, int n_in,
                              void* d_out, int out_size, void* d_ws, size_t ws_size,
                              hipStream_t stream) {
    // inputs (setup_inputs order):
    // 0 syllable (B,S,D) f32 — UNUSED by reference
    // 1 syllable_num (B,S) i32
    // 2 syllable_lengths (B,) i32
    // 3 beat_syb (B,S) f32
    // 4 ds_alf (B,S,P) f32
    // 5 label_xml (B,T) i32 — zeros, unused
    // 6 label_xml_lengths (B,) i32
    const int*   syllable_num     = (const int*)  d_in[1];
    const int*   syllable_lengths = (const int*)  d_in[2];
    const float* beat_syb         = (const float*)d_in[3];
    const float* ds_alf           = (const float*)d_in[4];
    const int*   label_lengths    = (const int*)  d_in[6];

    const int B = in_sizes[2];
    const int S = in_sizes[1] / B;
    const int T = in_sizes[5] / B;

    float* beat = (float*)d_out;

    const int chunks = (S + CHUNK - 1) / CHUNK;   // 16 for S=8192
    dim3 grid(chunks, B);
    plr_fused<<<grid, THREADS, 0, stream>>>(
        syllable_num, syllable_lengths, beat_syb, ds_alf,
        label_lengths, beat, beat + (size_t)B * T, S, T);
}

// Round 6
// 22.027 us; speedup vs baseline: 1.0005x; 1.0005x over previous
//
#include <hip/hip_runtime.h>

// -------------------------------------------------------------------------
// PhonemeLengthRegulator, single fused kernel, fully async front-end.
//   Phase order (all global traffic issued before any wait):
//     1. DMA ds_alf chunk -> LDS raw planes (global_load_lds, width 16)
//     2. tail-zero stores [len,T) slice + lengths output
//     3. prefix reduce (counts[0:chunk_start), L2-resident) + block scan
//     4. barrier (drains vmcnt: DMA + prefix complete)
//     5. masked softmax from LDS raw -> skewed LDS stage
//     6. barrier; coalesced float4 span write of beat[b, base:base+span)
//   raw plane layout: plane k holds thread t's k-th float4 at raw4[k*TH + t]
//   (global_load_lds writes wave-uniform base + lane*16 -> fits exactly).
// -------------------------------------------------------------------------

#define THREADS 256
#define CHUNK   256

__global__ __launch_bounds__(THREADS) void plr_fused(
        const int*   __restrict__ syllable_num,
        const int*   __restrict__ syllable_lengths,
        const float* __restrict__ beat_syb,
        const float* __restrict__ ds_alf,
        const int*   __restrict__ lens,
        float*       __restrict__ beat,
        float*       __restrict__ len_out,
        int S, int T) {
    const int b     = blockIdx.y;
    const int chunk = blockIdx.x;
    const int t     = threadIdx.x;
    const int lane  = t & 63;
    const int wid   = t >> 6;                 // 0..3

    __shared__ __align__(16) float4 raw4[4 * THREADS];      // 16 KB
    __shared__ __align__(16) float  stage[CHUNK * 16 + 4];  // 16 KB + pad
    __shared__ int wred[4];
    __shared__ int wsum[4];

    const int* nrow = syllable_num + (size_t)b * S;
    const int  j    = chunk * CHUNK + t;
    const bool in_s = (j < S);
    const bool dma_ok = ((chunk + 1) * CHUNK <= S);

    // ---- 1. async DMA: this chunk's logits -> LDS raw planes ----
    if (dma_ok) {
        const float* src = ds_alf + (((size_t)b * S + (size_t)chunk * CHUNK) << 4)
                         + (size_t)t * 16;
        #pragma unroll
        for (int k = 0; k < 4; ++k) {
            __builtin_amdgcn_global_load_lds(
                (const __attribute__((address_space(1))) unsigned int*)(src + 4 * k),
                (__attribute__((address_space(3))) unsigned int*)
                    &raw4[k * THREADS + (t & ~63)],
                16, 0, 0);
        }
    }

    const int slen = syllable_lengths[b];
    const int len  = lens[b];
    const int n    = in_s ? nrow[j] : 0;                  // 1..16 when valid

    // ---- 2. tail zero [len, T) slice + lengths out (store-only) ----
    float* row = beat + (size_t)b * T;
    if (chunk == 0 && t == 0) len_out[b] = (float)len;
    {
        const int fq   = len >> 2;
        const int Q    = T >> 2;
        const int nc   = gridDim.x;
        const int step = (Q - fq + nc - 1) / nc;
        const int q0   = fq + chunk * step;
        const int q1e  = q0 + step;
        const int q1   = (q1e < Q) ? q1e : Q;
        for (int q = q0 + t; q < q1; q += THREADS) {
            const int pos = q << 2;
            float* p = row + pos;
            if (pos >= len) {
                *(float4*)p = make_float4(0.f, 0.f, 0.f, 0.f);
            } else {
                #pragma unroll
                for (int k = 0; k < 4; ++k)
                    if (pos + k >= len) p[k] = 0.f;
            }
        }
    }

    // ---- 3. prefix reduce: sum counts[0 : chunk*CHUNK) masked by slen ----
    int pref = 0;
    {
        const int nv4 = (chunk * CHUNK) >> 2;             // multiple of 4
        const int4* nrow4 = (const int4*)nrow;
        for (int i = t; i < nv4; i += THREADS) {
            int4 v = nrow4[i];
            const int base = i << 2;
            pref += ((base + 0) < slen ? v.x : 0)
                  + ((base + 1) < slen ? v.y : 0)
                  + ((base + 2) < slen ? v.z : 0)
                  + ((base + 3) < slen ? v.w : 0);
        }
        #pragma unroll
        for (int d = 32; d >= 1; d >>= 1) pref += __shfl_xor(pref, d, 64);
    }
    if (lane == 0) wred[wid] = pref;

    // block-wide exclusive scan of this chunk's masked counts
    const int cnt = (in_s && j < slen) ? n : 0;
    int sc = cnt;
    #pragma unroll
    for (int d = 1; d < 64; d <<= 1) {
        int u = __shfl_up(sc, d, 64);
        if (lane >= d) sc += u;
    }
    if (lane == 63) wsum[wid] = sc;

    // ---- 4. barrier: also drains vmcnt -> DMA + prefix complete ----
    __syncthreads();

    int block_base = 0, wbase = 0, span = 0;
    #pragma unroll
    for (int w = 0; w < 4; ++w) {
        block_base += wred[w];
        span       += wsum[w];
        if (w < wid) wbase += wsum[w];
    }
    const int local_off = wbase + sc - cnt;               // exclusive offset
    const int skew      = block_base & 3;

    // ---- 5. masked softmax from raw planes -> skewed stage ----
    if (cnt > 0) {
        float x[16];
        if (dma_ok) {
            #pragma unroll
            for (int k = 0; k < 4; ++k) {
                float4 v = raw4[k * THREADS + t];
                x[4*k+0] = v.x; x[4*k+1] = v.y; x[4*k+2] = v.z; x[4*k+3] = v.w;
            }
        } else {
            const float4* src = (const float4*)(ds_alf + (((size_t)b * S + j) << 4));
            #pragma unroll
            for (int k = 0; k < 4; ++k) {
                float4 v = src[k];
                x[4*k+0] = v.x; x[4*k+1] = v.y; x[4*k+2] = v.z; x[4*k+3] = v.w;
            }
        }
        #pragma unroll
        for (int k = 0; k < 16; ++k)
            if (k >= n) x[k] = -INFINITY;                 // exp -> exactly 0

        float m = x[0];
        #pragma unroll
        for (int k = 1; k < 16; ++k) m = fmaxf(m, x[k]);

        float s = 0.0f;
        #pragma unroll
        for (int k = 0; k < 16; ++k) { x[k] = __expf(x[k] - m); s += x[k]; }

        const float scale = beat_syb[(size_t)b * S + j] * __builtin_amdgcn_rcpf(s);
        #pragma unroll
        for (int k = 0; k < 16; ++k)
            if (k < n) stage[skew + local_off + k] = x[k] * scale;
    }
    __syncthreads();

    // ---- 6. coalesced span write: beat[b, block_base : block_base+span) ----
    if (span > 0) {
        const int gbeg = block_base;
        const int gend = block_base + span;
        const int gal  = gbeg & ~3;                       // aligned-down
        const int a0   = (gbeg + 3) & ~3;                 // first aligned f4
        const int a1   = gend & ~3;                       // end of aligned body

        const int hn = ((a0 < gend) ? a0 : gend) - gbeg;  // scalar head (<=3)
        if (t < hn) row[gbeg + t] = stage[skew + t];

        for (int p = a0 + 4 * t; p + 4 <= gend; p += 4 * THREADS)
            *(float4*)(row + p) = *(const float4*)&stage[p - gal];

        const int tb = (a1 > a0) ? a1 : a0;               // scalar tail (<=3)
        if (tb < gend && t < gend - tb)
            row[tb + t] = stage[tb - gal + t];
    }
}

extern "C" void kernel_launch(void* const* d_in, const int* in_sizes, int n_in,
                              void* d_out, int out_size, void* d_ws, size_t ws_size,
                              hipStream_t stream) {
    // inputs (setup_inputs order):
    // 0 syllable (B,S,D) f32 — UNUSED by reference
    // 1 syllable_num (B,S) i32
    // 2 syllable_lengths (B,) i32
    // 3 beat_syb (B,S) f32
    // 4 ds_alf (B,S,P) f32
    // 5 label_xml (B,T) i32 — zeros, unused
    // 6 label_xml_lengths (B,) i32
    const int*   syllable_num     = (const int*)  d_in[1];
    const int*   syllable_lengths = (const int*)  d_in[2];
    const float* beat_syb         = (const float*)d_in[3];
    const float* ds_alf           = (const float*)d_in[4];
    const int*   label_lengths    = (const int*)  d_in[6];

    const int B = in_sizes[2];
    const int S = in_sizes[1] / B;
    const int T = in_sizes[5] / B;

    float* beat = (float*)d_out;

    const int chunks = (S + CHUNK - 1) / CHUNK;   // 32 for S=8192
    dim3 grid(chunks, B);
    plr_fused<<<grid, THREADS, 0, stream>>>(
        syllable_num, syllable_lengths, beat_syb, ds_alf,
        label_lengths, beat, beat + (size_t)B * T, S, T);
}